// Round 3
// baseline (64.681 us; speedup 1.0000x reference)
//
#include <hip/hip_runtime.h>

#define NN 2048
#define ROWS 16                       // rows per block
#define NBLK 512                      // 8192 / 16
#define HALF 16777216ull              // B*N*N = 4*2048*2048

typedef float __attribute__((ext_vector_type(4))) f32x4;

// Fused kernel:
//   h1 = relu(x @ Wmu1 + bmu1); h2 = h1 @ Wmu2 + bmu2; shift = 7*(h2.Wkp + bkp)
//   out[0..HALF)      = sigmoid((2 - 7j) + shift[row])      (adj_hard)
//   out[HALF..2HALF)  = (float)j                            (idxs: stable argsort of ties)
// 512 blocks x 256 threads; block owns 16 rows. Wave w owns rows w*4..w*4+3,
// lane owns cols 4*lane..4*lane+3. Weights staged in LDS 32 rows (32KB) at a
// time, shared by all 4 waves. idx stores trickled through the chunk loop to
// overlap the constant 64 MiB with MLP compute.
__global__ __launch_bounds__(256) void fused_dgg_kernel(
    const float* __restrict__ x,
    const float* __restrict__ Wmu1, const float* __restrict__ bmu1,
    const float* __restrict__ Wmu2, const float* __restrict__ bmu2,
    const float* __restrict__ Wkp,  const float* __restrict__ bkp,
    float* __restrict__ out)
{
    __shared__ float xs[128][20];     // x tile transposed [d][r], pad 20
    __shared__ float h1[256][20];     // h1 transposed [c][r]
    __shared__ float wbuf[32 * 256];  // staged weight chunk (32 rows x 256 cols)
    __shared__ float sh_shift[ROWS];

    const int t    = threadIdx.x;
    const int lane = t & 63;
    const int tr   = t >> 6;          // wave id = row group
    const int row0 = blockIdx.x * ROWS;

    // ---- stage x rows transposed ----
    {
        const int r = t >> 4, dq = t & 15;
        const float* src = x + (size_t)(row0 + r) * 128 + dq * 8;
        const float4 v0 = *(const float4*)(src);
        const float4 v1 = *(const float4*)(src + 4);
        const int d0 = dq * 8;
        xs[d0 + 0][r] = v0.x; xs[d0 + 1][r] = v0.y;
        xs[d0 + 2][r] = v0.z; xs[d0 + 3][r] = v0.w;
        xs[d0 + 4][r] = v1.x; xs[d0 + 5][r] = v1.y;
        xs[d0 + 6][r] = v1.z; xs[d0 + 7][r] = v1.w;
    }
    __syncthreads();

    // ---- helpers ----
    float* idxout = out + HALF + (size_t)row0 * NN;
    auto store_idx = [&](int k) {     // k-th of this thread's 32 idx float4s
        const int r    = k >> 1;
        const int j0   = t * 8 + (k & 1) * 4;
        f32x4 v = {(float)j0, (float)(j0 + 1), (float)(j0 + 2), (float)(j0 + 3)};
        __builtin_nontemporal_store(v, (f32x4*)(idxout + (size_t)r * NN + j0));
    };
    auto stageW = [&](const float* gsrc) {   // 32KB -> wbuf, reg-staged
        #pragma unroll
        for (int it = 0; it < 8; ++it) {
            const int off = it * 1024 + t * 4;            // floats
            const float4 v = *(const float4*)(gsrc + off);
            *(float4*)(wbuf + off) = v;
        }
    };

    // ---- layer 1: 128-deep, 4 chunks of 32 ----
    float acc[4][4] = {};
    for (int c = 0; c < 4; ++c) {
        stageW(Wmu1 + c * 32 * 256);
        for (int k = c * 3; k < c * 3 + 3 && k < 32; ++k) store_idx(k);
        __syncthreads();
        #pragma unroll 8
        for (int d = 0; d < 32; ++d) {
            const float4 av = *(const float4*)&xs[c * 32 + d][tr * 4];
            const float4 wv = *(const float4*)&wbuf[d * 256 + lane * 4];
            const float ar[4] = {av.x, av.y, av.z, av.w};
            const float wr[4] = {wv.x, wv.y, wv.z, wv.w};
            #pragma unroll
            for (int rr = 0; rr < 4; ++rr)
                #pragma unroll
                for (int j = 0; j < 4; ++j)
                    acc[rr][j] = fmaf(ar[rr], wr[j], acc[rr][j]);
        }
        __syncthreads();
    }

    // bias + relu -> h1 transposed
    {
        const float4 bv = *(const float4*)&bmu1[lane * 4];
        const float br[4] = {bv.x, bv.y, bv.z, bv.w};
        #pragma unroll
        for (int j = 0; j < 4; ++j)
            #pragma unroll
            for (int rr = 0; rr < 4; ++rr)
                h1[lane * 4 + j][tr * 4 + rr] = fmaxf(acc[rr][j] + br[j], 0.f);
    }

    // ---- layer 2: 256-deep, 8 chunks of 32 ----
    float acc2[4][4] = {};
    for (int c = 0; c < 8; ++c) {
        stageW(Wmu2 + c * 32 * 256);
        const int cc = 4 + c;
        for (int k = cc * 3; k < cc * 3 + 3 && k < 32; ++k) store_idx(k);
        __syncthreads();                  // wbuf ready; h1 visible (c==0)
        #pragma unroll 8
        for (int kk = 0; kk < 32; ++kk) {
            const float4 av = *(const float4*)&h1[c * 32 + kk][tr * 4];
            const float4 wv = *(const float4*)&wbuf[kk * 256 + lane * 4];
            const float ar[4] = {av.x, av.y, av.z, av.w};
            const float wr[4] = {wv.x, wv.y, wv.z, wv.w};
            #pragma unroll
            for (int rr = 0; rr < 4; ++rr)
                #pragma unroll
                for (int j = 0; j < 4; ++j)
                    acc2[rr][j] = fmaf(ar[rr], wr[j], acc2[rr][j]);
        }
        __syncthreads();
    }

    // ---- bias2 + dot with Wkp + wave reduce ----
    {
        const float4 b2 = *(const float4*)&bmu2[lane * 4];
        const float4 wk = *(const float4*)&Wkp[lane * 4];
        const float b2r[4] = {b2.x, b2.y, b2.z, b2.w};
        const float wkr[4] = {wk.x, wk.y, wk.z, wk.w};
        float p[4];
        #pragma unroll
        for (int rr = 0; rr < 4; ++rr) {
            float s = 0.f;
            #pragma unroll
            for (int j = 0; j < 4; ++j) s = fmaf(acc2[rr][j] + b2r[j], wkr[j], s);
            p[rr] = s;
        }
        #pragma unroll
        for (int off = 32; off > 0; off >>= 1)
            #pragma unroll
            for (int rr = 0; rr < 4; ++rr) p[rr] += __shfl_xor(p[rr], off, 64);
        if (lane == 0) {
            const float bk = bkp[0];
            #pragma unroll
            for (int rr = 0; rr < 4; ++rr)
                sh_shift[tr * 4 + rr] = 7.0f * (p[rr] + bk);
        }
    }
    __syncthreads();

    // ---- adj fill: sigmoid((2-7j) + shift) ----
    float* adj = out + (size_t)row0 * NN;
    const int j0 = t * 8;
    #pragma unroll 4
    for (int r = 0; r < ROWS; ++r) {
        const float s = sh_shift[r];
        float a[8];
        #pragma unroll
        for (int i = 0; i < 8; ++i) {
            const float z = (2.0f - 7.0f * (float)(j0 + i)) + s;
            a[i] = 1.0f / (1.0f + __expf(-z));
        }
        float* dst = adj + (size_t)r * NN + j0;
        f32x4 v0 = {a[0], a[1], a[2], a[3]};
        f32x4 v1 = {a[4], a[5], a[6], a[7]};
        __builtin_nontemporal_store(v0, (f32x4*)dst);
        __builtin_nontemporal_store(v1, (f32x4*)(dst + 4));
    }
}

extern "C" void kernel_launch(void* const* d_in, const int* in_sizes, int n_in,
                              void* d_out, int out_size, void* d_ws, size_t ws_size,
                              hipStream_t stream)
{
    (void)in_sizes; (void)n_in; (void)out_size; (void)d_ws; (void)ws_size;
    const float* x    = (const float*)d_in[0];
    // d_in[1] temp, d_in[2] W_in, d_in[3] b_in, d_in[4] w_dist, d_in[5] b_dist:
    // dead code (softmax over size-1 axis -> edge_prob == 1/N exactly,
    // stable argsort of ties -> identity permutation).
    const float* Wmu1 = (const float*)d_in[6];
    const float* bmu1 = (const float*)d_in[7];
    const float* Wmu2 = (const float*)d_in[8];
    const float* bmu2 = (const float*)d_in[9];
    const float* Wkp  = (const float*)d_in[10];
    const float* bkp  = (const float*)d_in[11];

    hipLaunchKernelGGL(fused_dgg_kernel, dim3(NBLK), dim3(256), 0, stream,
                       x, Wmu1, bmu1, Wmu2, bmu2, Wkp, bkp, (float*)d_out);
}

// Round 4
// 54.444 us; speedup vs baseline: 1.1880x; 1.1880x over previous
//
#include <hip/hip_runtime.h>

#define NN 2048
#define ROWS 16                       // rows per MLP block
#define NBLK_MLP 512                  // 8192 / 16
#define HALF 16777216ull              // B*N*N = 4*2048*2048

typedef float __attribute__((ext_vector_type(4))) f32x4;

// ---------------- Kernel 1: shift[row] = 7 * (k_net(x_row) + b_kp) ----------------
// h1 = relu(x @ Wmu1 + bmu1); h2 = h1 @ Wmu2 + bmu2; shift = 7*(h2.Wkp + bkp)
// 512 blocks x 256 threads, 16 rows/block. Wave w owns rows w*4..w*4+3, lane owns
// 4 contiguous cols. Weights staged in LDS 32 rows (32KB) at a time, shared by
// all 4 waves; no global stores inside the barrier loop.
__global__ __launch_bounds__(256) void mlp_kernel(
    const float* __restrict__ x,
    const float* __restrict__ Wmu1, const float* __restrict__ bmu1,
    const float* __restrict__ Wmu2, const float* __restrict__ bmu2,
    const float* __restrict__ Wkp,  const float* __restrict__ bkp,
    float* __restrict__ shift)
{
    __shared__ float xs[128][20];     // x tile transposed [d][r]
    __shared__ float h1[256][20];     // h1 transposed [c][r]
    __shared__ float wbuf[32 * 256];  // staged weight chunk

    const int t    = threadIdx.x;
    const int lane = t & 63;
    const int tr   = t >> 6;
    const int row0 = blockIdx.x * ROWS;

    // stage x rows transposed
    {
        const int r = t >> 4, dq = t & 15;
        const float* src = x + (size_t)(row0 + r) * 128 + dq * 8;
        const float4 v0 = *(const float4*)(src);
        const float4 v1 = *(const float4*)(src + 4);
        const int d0 = dq * 8;
        xs[d0 + 0][r] = v0.x; xs[d0 + 1][r] = v0.y;
        xs[d0 + 2][r] = v0.z; xs[d0 + 3][r] = v0.w;
        xs[d0 + 4][r] = v1.x; xs[d0 + 5][r] = v1.y;
        xs[d0 + 6][r] = v1.z; xs[d0 + 7][r] = v1.w;
    }

    auto stageW = [&](const float* gsrc) {
        #pragma unroll
        for (int it = 0; it < 8; ++it) {
            const int off = it * 1024 + t * 4;
            const float4 v = *(const float4*)(gsrc + off);
            *(float4*)(wbuf + off) = v;
        }
    };

    __syncthreads();

    // layer 1: 128-deep, 4 chunks of 32
    float acc[4][4] = {};
    for (int c = 0; c < 4; ++c) {
        stageW(Wmu1 + c * 32 * 256);
        __syncthreads();
        #pragma unroll 8
        for (int d = 0; d < 32; ++d) {
            const float4 av = *(const float4*)&xs[c * 32 + d][tr * 4];   // broadcast
            const float4 wv = *(const float4*)&wbuf[d * 256 + lane * 4]; // b128, no conflict
            const float ar[4] = {av.x, av.y, av.z, av.w};
            const float wr[4] = {wv.x, wv.y, wv.z, wv.w};
            #pragma unroll
            for (int rr = 0; rr < 4; ++rr)
                #pragma unroll
                for (int j = 0; j < 4; ++j)
                    acc[rr][j] = fmaf(ar[rr], wr[j], acc[rr][j]);
        }
        __syncthreads();
    }

    // bias + relu -> h1 transposed
    {
        const float4 bv = *(const float4*)&bmu1[lane * 4];
        const float br[4] = {bv.x, bv.y, bv.z, bv.w};
        #pragma unroll
        for (int j = 0; j < 4; ++j)
            #pragma unroll
            for (int rr = 0; rr < 4; ++rr)
                h1[lane * 4 + j][tr * 4 + rr] = fmaxf(acc[rr][j] + br[j], 0.f);
    }

    // layer 2: 256-deep, 8 chunks of 32
    float acc2[4][4] = {};
    for (int c = 0; c < 8; ++c) {
        stageW(Wmu2 + c * 32 * 256);
        __syncthreads();                  // wbuf ready; h1 visible (c==0)
        #pragma unroll 8
        for (int kk = 0; kk < 32; ++kk) {
            const float4 av = *(const float4*)&h1[c * 32 + kk][tr * 4];
            const float4 wv = *(const float4*)&wbuf[kk * 256 + lane * 4];
            const float ar[4] = {av.x, av.y, av.z, av.w};
            const float wr[4] = {wv.x, wv.y, wv.z, wv.w};
            #pragma unroll
            for (int rr = 0; rr < 4; ++rr)
                #pragma unroll
                for (int j = 0; j < 4; ++j)
                    acc2[rr][j] = fmaf(ar[rr], wr[j], acc2[rr][j]);
        }
        __syncthreads();
    }

    // bias2 + dot with Wkp + wave reduce
    {
        const float4 b2 = *(const float4*)&bmu2[lane * 4];
        const float4 wk = *(const float4*)&Wkp[lane * 4];
        const float b2r[4] = {b2.x, b2.y, b2.z, b2.w};
        const float wkr[4] = {wk.x, wk.y, wk.z, wk.w};
        float p[4];
        #pragma unroll
        for (int rr = 0; rr < 4; ++rr) {
            float s = 0.f;
            #pragma unroll
            for (int j = 0; j < 4; ++j) s = fmaf(acc2[rr][j] + b2r[j], wkr[j], s);
            p[rr] = s;
        }
        #pragma unroll
        for (int off = 32; off > 0; off >>= 1)
            #pragma unroll
            for (int rr = 0; rr < 4; ++rr) p[rr] += __shfl_xor(p[rr], off, 64);
        if (lane == 0) {
            const float bk = bkp[0];
            #pragma unroll
            for (int rr = 0; rr < 4; ++rr)
                shift[row0 + tr * 4 + rr] = 7.0f * (p[rr] + bk);
        }
    }
}

// ---------------- Kernel 2: fill both output halves ----------------
// out[0..HALF)     : adj[row][j] = sigmoid((2 - 7j) + shift[row])
// out[HALF..2HALF) : idx[row][j] = (float)j
// 2048 blocks x 256 threads; wave owns one row (4 rows/block). Each store
// instruction covers 1KB contiguous per wave (col = i*256 + lane*4).
__global__ __launch_bounds__(256) void fill_kernel(
    const float* __restrict__ shift, float* __restrict__ out)
{
    const int t    = threadIdx.x;
    const int lane = t & 63;
    const int w    = t >> 6;
    const int row  = blockIdx.x * 4 + w;
    const float s  = 2.0f + shift[row];

    float* adj = out + (size_t)row * NN;
    float* idx = out + HALF + (size_t)row * NN;

    #pragma unroll
    for (int i = 0; i < 8; ++i) {
        const int c = i * 256 + lane * 4;
        f32x4 a, v;
        #pragma unroll
        for (int q = 0; q < 4; ++q) {
            const float j = (float)(c + q);
            const float z = fmaf(-7.0f, j, s);
            a[q] = 1.0f / (1.0f + __expf(-z));   // overflow -> inf -> 0, exact enough
            v[q] = j;
        }
        *(f32x4*)(adj + c) = a;
        *(f32x4*)(idx + c) = v;
    }
}

extern "C" void kernel_launch(void* const* d_in, const int* in_sizes, int n_in,
                              void* d_out, int out_size, void* d_ws, size_t ws_size,
                              hipStream_t stream)
{
    (void)in_sizes; (void)n_in; (void)out_size; (void)ws_size;
    const float* x    = (const float*)d_in[0];
    // d_in[1] temp, d_in[2] W_in, d_in[3] b_in, d_in[4] w_dist, d_in[5] b_dist:
    // dead code (softmax over size-1 axis -> edge_prob == 1/N exactly,
    // stable argsort of ties -> identity permutation).
    const float* Wmu1 = (const float*)d_in[6];
    const float* bmu1 = (const float*)d_in[7];
    const float* Wmu2 = (const float*)d_in[8];
    const float* bmu2 = (const float*)d_in[9];
    const float* Wkp  = (const float*)d_in[10];
    const float* bkp  = (const float*)d_in[11];

    float* shift = (float*)d_ws;      // 8192 floats
    float* out   = (float*)d_out;

    hipLaunchKernelGGL(mlp_kernel, dim3(NBLK_MLP), dim3(256), 0, stream,
                       x, Wmu1, bmu1, Wmu2, bmu2, Wkp, bkp, shift);
    hipLaunchKernelGGL(fill_kernel, dim3(8192 / 4), dim3(256), 0, stream,
                       shift, out);
}